// Round 16
// baseline (227.542 us; speedup 1.0000x reference)
//
#include <hip/hip_runtime.h>
#include <math.h>

#define UNITS 64
#define TT 100
#define NROW 32        // sequences per block (packed 2-per-slot)
#define NSLOT 16       // MFMA M-rows (slots)
#define NTH 256        // 4 waves; wave w owns unit-columns [16w,16w+16) for all 4 gates
#define HSTR 72        // h row stride in halves
#define XQS 34         // xq quad stride per timestep (32 rows + 2 pad)

typedef _Float16 half8 __attribute__((ext_vector_type(8)));
typedef _Float16 half4 __attribute__((ext_vector_type(4)));
typedef float floatx4 __attribute__((ext_vector_type(4)));

#define LOG2E 1.44269504088896f

__device__ __forceinline__ float rcp_fast(float x) { return __builtin_amdgcn_rcpf(x); }
__device__ __forceinline__ float exp2_fast(float x) { return __builtin_amdgcn_exp2f(x); }

__device__ __forceinline__ float fast_sigmoid(float x) {
    return rcp_fast(1.0f + exp2_fast(-LOG2E * x));      // saturates correctly
}
__device__ __forceinline__ float fast_tanh(float x) {
    return __builtin_fmaf(2.0f, rcp_fast(1.0f + exp2_fast(-2.0f * LOG2E * x)), -1.0f);
}

// Ledger (r5..r15): wall time ~ executed block-steps / ~550 steps/us; extra graph
// nodes cost 30-75 us; ANY cross-block sync at scale costs 300+ us. So: ONE node,
// and cut steps in-block: 32 rows/block, local length-sort, pair rank s with 31-s
// into 16 slots, each slot chains long-then-short sequence (h,c reset at switch).
// Slot totals concentrate ~120 -> block steps ~131 vs ~190 for two unsorted tiles.
// Dead/chained slots run unmasked: sigmoid/tanh bound everything (|h|<=1), rows are
// independent through MFMA, outputs come only from hfin snapshots at seq ends.
__global__ __launch_bounds__(NTH, 2) void lstm_packed_kernel(
    const float* __restrict__ x,    // (B,100,3)
    const float* __restrict__ W,    // (3,256)
    const float* __restrict__ U,    // (64,256)
    const float* __restrict__ bias, // (256,)
    const float* __restrict__ W1,   // (64,64)
    const float* __restrict__ b1,   // (64,)
    const float* __restrict__ W2,   // (64,5)
    const float* __restrict__ b2,   // (5,)
    float* __restrict__ out, int B)
{
    __shared__ __align__(16) _Float16 hb[2][NSLOT * HSTR]; // double-buffered slot h
    __shared__ __align__(16) _Float16 xq[TT * XQS * 4];    // staged x quads {x0,x1,x2,1}
    __shared__ __align__(16) _Float16 hfin[NROW * HSTR];   // final h per ROW (snapshot)
    __shared__ __align__(16) _Float16 zq[8];               // zero quad for q!=0 AX reads
    __shared__ int llen_s[NROW];
    __shared__ int sortedIdx[NROW];
    __shared__ int slotA[NSLOT], slotB[NSLOT], slotLA[NSLOT], slotTL[NSLOT];
    __shared__ float h1buf[NROW * 64];
    __shared__ float logitbuf[NROW * 5];

    const int tid = threadIdx.x;
    const int w   = tid >> 6;
    const int l   = tid & 63;
    const int q   = l >> 4;
    const int cnl = l & 15;
    const int g0  = blockIdx.x * NROW;
    const int rower = tid >> 3;   // 0..31: row for length/staging duty
    const int s8    = tid & 7;    // lane within row group

    // ---- per-row lengths: 8 lanes/row, coalesced ----
    {
        const float* xp = x + (size_t)(g0 + rower) * (TT * 3);
        int m = 0;
        for (int t = s8; t < TT; t += 8) {
            const float a = xp[3*t], b = xp[3*t+1], c = xp[3*t+2];
            if (a != 0.0f || b != 0.0f || c != 0.0f) m = t + 1;
        }
        #pragma unroll
        for (int off = 4; off; off >>= 1) m = max(m, __shfl_down(m, off, 8));
        if (s8 == 0) llen_s[rower] = m;
    }
    // ---- zero LDS state ----
    if (tid < 8) zq[tid] = (_Float16)0.0f;
    for (int i = tid; i < NSLOT * HSTR; i += NTH) hb[0][i] = (_Float16)0.0f;
    for (int i = tid; i < NROW * HSTR; i += NTH) hfin[i] = (_Float16)0.0f;
    for (int i = tid; i < TT * XQS * 4; i += NTH) xq[i] = (_Float16)0.0f;

    // ---- extended-K B fragments (global loads; overlap the sort) ----
    // Rows 0..63=U, 64..66=W, 67=bias, 68..95=0. Lane holds B[k=32kb+8q+j][zc].
    half8 Bf[4][3];
    #pragma unroll
    for (int g = 0; g < 4; ++g) {
        const int zc = 64 * g + 16 * w + cnl;
        #pragma unroll
        for (int kb = 0; kb < 3; ++kb)
            #pragma unroll
            for (int j = 0; j < 8; ++j) {
                const int k = 32 * kb + 8 * q + j;
                float v = 0.0f;
                if (k < 64)       v = U[k * 256 + zc];
                else if (k < 67)  v = W[(k - 64) * 256 + zc];
                else if (k == 67) v = bias[zc];
                Bf[g][kb][j] = (_Float16)v;
            }
    }

    __syncthreads();   // llen_s + LDS zeros visible (round-7 lesson)

    // ---- in-block rank sort (descending, stable) ----
    if (tid < NROW) {
        const int li = llen_s[tid];
        int rank = 0;
        for (int j = 0; j < NROW; ++j) {
            const int lj = llen_s[j];
            rank += (lj > li) || (lj == li && j < tid);
        }
        sortedIdx[rank] = tid;
    }
    __syncthreads();
    if (tid < NSLOT) {
        const int a = sortedIdx[tid];             // long
        const int b = sortedIdx[NROW - 1 - tid];  // short (pair sums ~ constant)
        slotA[tid] = a; slotB[tid] = b;
        const int la = llen_s[a];
        slotLA[tid] = la;
        slotTL[tid] = la + llen_s[b];
    }
    // ---- stage xq: row `rower`, steps s8..len step 8 ----
    {
        const float* xp = x + (size_t)(g0 + rower) * (TT * 3);
        const int myl = llen_s[rower];
        for (int t = s8; t < myl; t += 8) {
            half4 v = { (_Float16)xp[3*t], (_Float16)xp[3*t+1],
                        (_Float16)xp[3*t+2], (_Float16)1.0f };
            *(half4*)&xq[(t * XQS + rower) * 4] = v;
        }
    }
    __syncthreads();   // slot arrays + staging visible

    // ---- per-lane slot registers (slot = 4q+r for update duty; cnl for AX duty) ----
    int lAr[4], TLr[4], rAr[4], rBr[4];
    #pragma unroll
    for (int r = 0; r < 4; ++r) {
        const int s = 4 * q + r;
        lAr[r] = slotLA[s]; TLr[r] = slotTL[s];
        rAr[r] = slotA[s];  rBr[r] = slotB[s];
    }
    const int xsLA = slotLA[cnl], xsRowA = slotA[cnl], xsRowB = slotB[cnl];
    int maxstep = 0;
    #pragma unroll
    for (int i = 0; i < NSLOT; ++i) maxstep = max(maxstep, slotTL[i]);
    maxstep = (maxstep < 0) ? 0 : ((maxstep > 2 * TT) ? 2 * TT : maxstep);

    float c4[4] = {0.0f, 0.0f, 0.0f, 0.0f};
    _Float16 hcur[4] = {(_Float16)0.0f, (_Float16)0.0f, (_Float16)0.0f, (_Float16)0.0f};
    const floatx4 zero4 = {0.0f, 0.0f, 0.0f, 0.0f};
    const int col = 16 * w + cnl;

    #pragma unroll 1
    for (int t = 0; t < maxstep; ++t) {
        const _Float16* hbc = hb[t & 1];
        _Float16*       hbn = hb[(t + 1) & 1];

        // A fragments: lane holds A[m=cnl][k = 32*kb + 8q + j]
        const half8 A0 = *(const half8*)&hbc[cnl * HSTR + 8 * q];
        const half8 A1 = *(const half8*)&hbc[cnl * HSTR + 32 + 8 * q];
        // AX: q0 lane cnl feeds slot cnl's current sequence at its local timestep
        const int inA  = (t < xsLA);
        const int xrow = inA ? xsRowA : xsRowB;
        int tl = inA ? t : (t - xsLA);
        tl = (tl > TT - 1) ? (TT - 1) : tl;   // dead-slot clamp (reads zeros; bounded)
        const _Float16* xaddr = (q == 0) ? &xq[(tl * XQS + xrow) * 4] : zq;
        const half4 x4 = *(const half4*)xaddr;
        const half8 AX = { x4[0], x4[1], x4[2], x4[3],
                           (_Float16)0.0f, (_Float16)0.0f, (_Float16)0.0f, (_Float16)0.0f };

        floatx4 acc[4];
        #pragma unroll
        for (int g = 0; g < 4; ++g) {
            acc[g] = __builtin_amdgcn_mfma_f32_16x16x32_f16(AX, Bf[g][2], zero4, 0, 0, 0);
            acc[g] = __builtin_amdgcn_mfma_f32_16x16x32_f16(A0, Bf[g][0], acc[g], 0, 0, 0);
            acc[g] = __builtin_amdgcn_mfma_f32_16x16x32_f16(A1, Bf[g][1], acc[g], 0, 0, 0);
        }

        #pragma unroll
        for (int r = 0; r < 4; ++r) {
            const float iv = fast_sigmoid(acc[0][r]);
            const float fv = fast_sigmoid(acc[1][r]);
            const float gv = fast_tanh  (acc[2][r]);
            const float ov = fast_sigmoid(acc[3][r]);
            const float cn = fv * c4[r] + iv * gv;          // unconditional (bounded)
            const _Float16 hn = (_Float16)(ov * fast_tanh(cn));
            const bool aEnd = (t == lAr[r] - 1);            // seqA final step
            const bool bEnd = (t == TLr[r] - 1);            // seqB final step
            if (aEnd) hfin[rAr[r] * HSTR + col] = hn;       // snapshot finals
            if (bEnd) hfin[rBr[r] * HSTR + col] = hn;
            c4[r]   = aEnd ? 0.0f : cn;                     // reset for seqB start
            hcur[r] = aEnd ? (_Float16)0.0f : hn;
            hbn[(4 * q + r) * HSTR + col] = hcur[r];
        }
        __syncthreads();
    }

    // ---- epilogue on hfin (32 rows): h1 = relu(hfin @ W1 + b1) ----
    {
        const int j  = tid & 63;
        const int bb = tid >> 6;
        const float bj = b1[j];
        #pragma unroll
        for (int p = 0; p < NROW / 4; ++p) {
            const int b = p * 4 + bb;
            float acc = bj;
            #pragma unroll 8
            for (int k = 0; k < UNITS; ++k)
                acc += (float)hfin[b * HSTR + k] * W1[k * 64 + j];
            h1buf[b * 64 + j] = fmaxf(acc, 0.0f);
        }
    }
    __syncthreads();

    if (tid < NROW * 5) {
        const int b = tid / 5, s = tid % 5;
        float acc = b2[s];
        for (int j = 0; j < 64; ++j)
            acc += h1buf[b * 64 + j] * W2[j * 5 + s];
        logitbuf[b * 5 + s] = acc;
    }
    __syncthreads();

    if (tid < NROW) {
        const int gb = g0 + tid;   // hfin indexed by ORIGINAL local row -> identity out
        const float l0 = logitbuf[tid * 5 + 0];
        const float l1 = logitbuf[tid * 5 + 1];
        const float l2 = logitbuf[tid * 5 + 2];
        const float l3 = logitbuf[tid * 5 + 3];
        const float l4 = logitbuf[tid * 5 + 4];
        const float m  = fmaxf(fmaxf(fmaxf(l0, l1), fmaxf(l2, l3)), l4);
        const float e0 = __expf(l0 - m), e1 = __expf(l1 - m), e2 = __expf(l2 - m);
        const float e3 = __expf(l3 - m), e4 = __expf(l4 - m);
        const float rs = 1.0f / (e0 + e1 + e2 + e3 + e4);
        out[(size_t)gb * 5 + 0] = e0 * rs;
        out[(size_t)gb * 5 + 1] = e1 * rs;
        out[(size_t)gb * 5 + 2] = e2 * rs;
        out[(size_t)gb * 5 + 3] = e3 * rs;
        out[(size_t)gb * 5 + 4] = e4 * rs;
    }
}

extern "C" void kernel_launch(void* const* d_in, const int* in_sizes, int n_in,
                              void* d_out, int out_size, void* d_ws, size_t ws_size,
                              hipStream_t stream) {
    const float* x  = (const float*)d_in[0];
    const float* W  = (const float*)d_in[1];
    const float* U  = (const float*)d_in[2];
    const float* b  = (const float*)d_in[3];
    const float* W1 = (const float*)d_in[4];
    const float* b1 = (const float*)d_in[5];
    const float* W2 = (const float*)d_in[6];
    const float* b2 = (const float*)d_in[7];
    float* out = (float*)d_out;

    const int B = in_sizes[0] / (TT * 3);   // 16384

    lstm_packed_kernel<<<dim3(B / NROW), dim3(NTH), 0, stream>>>(
        x, W, U, b, W1, b1, W2, b2, out, B);
}